// Round 6
// baseline (5439.436 us; speedup 1.0000x reference)
//
#include <hip/hip_runtime.h>
#include <hip/hip_fp16.h>

// LSTM B=8192 S=1024 H=256 — round 13: wave-group ANTIPHASE (4-phase step).
// r12 post-mortem: EW-first pipelining was fine; poll at 0-phase slack was the
// regression (FETCH +12MB stale-spin signature). Root structural limit: both
// waves on a SIMD are barrier-locked into the SAME phase -> VALU (EW) and
// matrix (K) pipes never overlap. This round: 8 waves -> 2 groups of 4,
// grp=(wv&1)^((wv>>2)&1) so EVERY SIMD holds one wave of each group under
// either wave->SIMD mapping. 4 barrier-phases per step t:
//    g0: K(0,t) | EW(0,t) | K(1,t) | EW(1,t)
//    g1: EW(1,t-1) | K(0,t) | EW(0,t) | K(1,t)
// -> every phase pairs one MFMA-role with one VALU-role wave per SIMD.
// Flags: flag[1]=t after p1, flag[0]=t+1 after p3 -> every poll target is a
// FULL PHASE old (fresh regime, the r9/r11/r12 lesson). Lead group (g0)
// polls + DMAs the peer half DUPLICATED per wave (all 32 rows each; benign
// identical-write race) so its own vmcnt(0) between hm0/hm1 suffices; g1
// inherits via the phase barrier. Own-half h ds_written at EW (parity-
// double-buffered stg, 64KB). WAR on pub transitively gated by the polls.
// acc back to ONE set (32 VGPR): filled in K-phase, drained next-phase EW.
// EW: 7 trans/elem (5 exp2 + 2 rcp), weights pre-scaled by log2e (x2 c gate).
// 256 blocks x 512 thr, 1 block/CU; pairs {B,B^8} (same XCD) share 64 rows.

typedef _Float16 f16x8 __attribute__((ext_vector_type(8)));
typedef float f32x4 __attribute__((ext_vector_type(4)));
typedef unsigned int u32;
typedef unsigned short u16;

#define WINT_OFF 0u
#define W0B_OFF  524288u
#define FLAG_OFF 528384u   // int[256 blocks][2 sets][16] = 32 KB
#define PUB_OFF  1048576u  // u16[(set*2+par)*128+pair][2 half][4096] = 8 MB

static __device__ __forceinline__ float fast_exp2(float x) {
#if __has_builtin(__builtin_amdgcn_exp2f)
  return __builtin_amdgcn_exp2f(x);
#else
  return exp2f(x);
#endif
}
static __device__ __forceinline__ float fast_rcp(float x) {
#if __has_builtin(__builtin_amdgcn_rcpf)
  return __builtin_amdgcn_rcpf(x);
#else
  return 1.0f / x;
#endif
}
static __device__ __forceinline__ u16 f16b(float f) {
  union { _Float16 h; u16 u; } cv; cv.h = (_Float16)f; return cv.u;
}
static __device__ __forceinline__ float h2f(u16 u) {
  union { u16 u; _Float16 h; } cv; cv.u = u; return (float)cv.h;
}
static __device__ __forceinline__ u16* pub_base(u16* pub, int set, int par,
                                                int pid, int half) {
  return pub + ((size_t)(((set * 2 + par) * 128 + pid) * 2 + half) << 12);
}

// Wint[n][k], n = g*256 + j, PRE-SCALED by log2e (x2 for the c gate);
// w0b[n] = packed fp16 {w0*scale, bias*scale}.
__global__ void lstm_prep(const float* __restrict__ Wf, const float* __restrict__ Wi,
                          const float* __restrict__ Wc, const float* __restrict__ Wo,
                          const float* __restrict__ bf_, const float* __restrict__ bi_,
                          const float* __restrict__ bc_, const float* __restrict__ bo_,
                          u16* __restrict__ Wint, u32* __restrict__ w0b) {
  int n = blockIdx.x;       // 0..1023
  int k = threadIdx.x;      // 0..255
  int g = n >> 8, j = n & 255;
  const float* Ws = (g == 0) ? Wf : (g == 1) ? Wi : (g == 2) ? Wc : Wo;
  const float scale = (g == 2) ? 2.88539008f : 1.44269504f;  // 2*log2e : log2e
  Wint[n * 256 + k] = f16b(Ws[j * 257 + 1 + k] * scale);
  if (k == 0) {
    const float* bs = (g == 0) ? bf_ : (g == 1) ? bi_ : (g == 2) ? bc_ : bo_;
    w0b[n] = (u32)f16b(Ws[j * 257] * scale) | ((u32)f16b(bs[j] * scale) << 16);
  }
}

// Zero parity-0 pub of both sets (h_0 = 0), flags, out = bout.
__global__ void lstm_zero(uint4* __restrict__ pub4, uint4* __restrict__ flags4,
                          float* __restrict__ out, const float* __restrict__ bout) {
  int idx = blockIdx.x * 256 + threadIdx.x;
  uint4 z = uint4{0, 0, 0, 0};
  if (idx < 131072) pub4[idx] = z;                 // slot (s0,p0): 2 MB
  else if (idx < 262144) pub4[idx + 131072] = z;   // slot (s1,p0): 2 MB
  else if (idx < 264192) flags4[idx - 262144] = z; // 32 KB flags
  else { int o = idx - 264192; if (o < 8192) out[o] = bout[0]; }
}

__global__ __launch_bounds__(512, 2) void lstm_main(
    const u16* __restrict__ Wint, const u32* __restrict__ w0b,
    const float* __restrict__ x, const float* __restrict__ Wout,
    float* __restrict__ out, u16* __restrict__ pub, int* __restrict__ flags) {

  // [set][parity][0=own k-half,1=peer][32 rows x 128 cols] = 64 KB
  __shared__ __align__(16) u16 stg[2][2][2][4096];

  const int tid  = threadIdx.x;
  const int wv   = tid >> 6;
  const int lane = tid & 63;
  const int l15  = lane & 15;
  const int quad = lane >> 4;
  const int grp  = (wv & 1) ^ ((wv >> 2) & 1);  // 4/4; one of each per SIMD
  const int B    = blockIdx.x;
  const int mi   = (B >> 3) & 1;
  const int peer = B ^ 8;
  const int pid  = (B & 7) | ((B >> 4) << 3);   // pair 0..127
  const int rows0 = pid * 64;

  // ---- one-time: W A-fragments (128 regs, STATIC indices) ----
  f16x8 wfrag[4][8];
#pragma unroll
  for (int g = 0; g < 4; ++g)
#pragma unroll
    for (int hm = 0; hm < 2; ++hm)
#pragma unroll
      for (int ktl = 0; ktl < 4; ++ktl) {
        int kbase = (hm == 0 ? mi : 1 - mi) * 128 + ktl * 32;  // runtime, addr only
        wfrag[g][hm * 4 + ktl] = *(const f16x8*)(Wint +
            (size_t)(g * 256 + mi * 128 + wv * 16 + l15) * 256 + kbase + quad * 8);
      }
  // one-time unpack of w0/bias to f32 (loop-invariant)
  float w0f[4][4], bsf[4][4];
#pragma unroll
  for (int g = 0; g < 4; ++g) {
    uint4 wv4 = *(const uint4*)(w0b + g * 256 + mi * 128 + wv * 16 + quad * 4);
    u32 pka[4] = {wv4.x, wv4.y, wv4.z, wv4.w};
#pragma unroll
    for (int r = 0; r < 4; ++r) {
      w0f[g][r] = h2f((u16)pka[r]);
      bsf[g][r] = h2f((u16)(pka[r] >> 16));
    }
  }

  // zero stg (h_0 images = 0): 64 KB = 4096 uint4
#pragma unroll
  for (int i = 0; i < 8; ++i) ((uint4*)stg)[tid + i * 512] = uint4{0, 0, 0, 0};

  float cst[2][2][4];   // [set][bt][r]: cell (b = bt*16+l15, j = wv*16+quad*4+r)
#pragma unroll
  for (int s = 0; s < 2; ++s)
#pragma unroll
    for (int bt = 0; bt < 2; ++bt)
#pragma unroll
      for (int r = 0; r < 4; ++r) cst[s][bt][r] = 0.0f;

  f32x4 acc[4][2];   // ONE set live per wave (filled in K, drained next EW)

  const float* xq = x + (size_t)rows0 * 1024;
  float xcur[2][2];
#pragma unroll
  for (int s = 0; s < 2; ++s)
#pragma unroll
    for (int bt = 0; bt < 2; ++bt)
      xcur[s][bt] = xq[(size_t)(s * 32 + bt * 16 + l15) * 1024];

  int* const myflag = flags + B * 32;
  int* const pfl    = flags + peer * 32;

  __syncthreads();

// K for set S at step T. LEAD=1: poll peer flag + duplicated DMA of the full
// peer half (this wave loads ALL 32 rows -> its own vmcnt(0) covers its reads;
// identical-value LDS write race across lead waves is benign).
#define DO_K(S, T, LEAD) do {                                                  \
    const int par_ = (T) & 1;                                                  \
    if (LEAD) {                                                                \
      while (__hip_atomic_load(pfl + (S) * 16, __ATOMIC_RELAXED,               \
                               __HIP_MEMORY_SCOPE_AGENT) < (T))                \
        __builtin_amdgcn_s_sleep(1);                                           \
      const u16* srcP_ = pub_base(pub, (S), par_, pid, 1 - mi);                \
      u16* dst_ = &stg[S][par_][1][0];                                         \
      _Pragma("unroll")                                                        \
      for (int i_ = 0; i_ < 8; ++i_)                                           \
        __builtin_amdgcn_global_load_lds(                                      \
            (const __attribute__((address_space(1))) u32*)(srcP_ + i_ * 512 + lane * 8), \
            (__attribute__((address_space(3))) u32*)(dst_ + i_ * 512), 16, 0, 0); \
      __builtin_amdgcn_sched_barrier(0);                                       \
    }                                                                          \
    _Pragma("unroll")                                                          \
    for (int g_ = 0; g_ < 4; ++g_)                                             \
      _Pragma("unroll")                                                        \
      for (int r_ = 0; r_ < 4; ++r_) {                                         \
        acc[g_][0][r_] = xcur[S][0] * w0f[g_][r_] + bsf[g_][r_];               \
        acc[g_][1][r_] = xcur[S][1] * w0f[g_][r_] + bsf[g_][r_];               \
      }                                                                        \
    _Pragma("unroll")                                                          \
    for (int ktl_ = 0; ktl_ < 4; ++ktl_) {                                     \
      f16x8 bb_[2];                                                            \
      _Pragma("unroll")                                                        \
      for (int bt_ = 0; bt_ < 2; ++bt_) {                                      \
        int b_ = bt_ * 16 + l15;                                               \
        int cp_ = (ktl_ * 4 + quad) ^ (b_ & 15);                               \
        bb_[bt_] = *(const f16x8*)(&stg[S][par_][0][0] + b_ * 128 + cp_ * 8);  \
      }                                                                        \
      _Pragma("unroll")                                                        \
      for (int g_ = 0; g_ < 4; ++g_)                                           \
        _Pragma("unroll")                                                      \
        for (int bt_ = 0; bt_ < 2; ++bt_)                                      \
          acc[g_][bt_] = __builtin_amdgcn_mfma_f32_16x16x32_f16(               \
              wfrag[g_][ktl_], bb_[bt_], acc[g_][bt_], 0, 0, 0);               \
    }                                                                          \
    if (LEAD) {                                                                \
      asm volatile("s_waitcnt vmcnt(0)" ::: "memory");                         \
      __builtin_amdgcn_sched_barrier(0);                                       \
    }                                                                          \
    _Pragma("unroll")                                                          \
    for (int ktl_ = 0; ktl_ < 4; ++ktl_) {                                     \
      f16x8 bb_[2];                                                            \
      _Pragma("unroll")                                                        \
      for (int bt_ = 0; bt_ < 2; ++bt_) {                                      \
        int b_ = bt_ * 16 + l15;                                               \
        int cp_ = (ktl_ * 4 + quad) ^ (b_ & 15);                               \
        bb_[bt_] = *(const f16x8*)(&stg[S][par_][1][0] + b_ * 128 + cp_ * 8);  \
      }                                                                        \
      _Pragma("unroll")                                                        \
      for (int g_ = 0; g_ < 4; ++g_)                                           \
        _Pragma("unroll")                                                      \
        for (int bt_ = 0; bt_ < 2; ++bt_)                                      \
          acc[g_][bt_] = __builtin_amdgcn_mfma_f32_16x16x32_f16(               \
              wfrag[g_][4 + ktl_], bb_[bt_], acc[g_][bt_], 0, 0, 0);           \
    }                                                                          \
  } while (0)

// EW for set S: consume acc (this wave's last K(S)), update cst[S], publish
// h_{TEW+1}(S): ds_write own half (parity (TEW+1)&1) + global pub.
#define DO_EW(S, TEW) do {                                                     \
    const int parn_ = ((TEW) + 1) & 1;                                         \
    u16* pb_ = pub_base(pub, (S), parn_, pid, mi);                             \
    u16* lb_ = &stg[S][parn_][0][0];                                           \
    _Pragma("unroll")                                                          \
    for (int bt_ = 0; bt_ < 2; ++bt_) {                                        \
      int b_ = bt_ * 16 + l15;                                                 \
      u32 lo_, hi_;                                                            \
      {                                                                        \
        float h0_, h1_, h2_, h3_;                                              \
        _Pragma("unroll")                                                      \
        for (int r_ = 0; r_ < 4; ++r_) {                                       \
          float fg_ = acc[0][bt_][r_], ig_ = acc[1][bt_][r_];                  \
          float cg_ = acc[2][bt_][r_], og_ = acc[3][bt_][r_];                  \
          float Ef_ = fast_exp2(-fg_);                                         \
          float Ei_ = fast_exp2(-ig_);                                         \
          float C_  = fast_exp2(cg_);                                          \
          float X_  = 1.0f + Ef_;                                              \
          float Y_  = (1.0f + Ei_) * (C_ + 1.0f);                              \
          float num_ = cst[S][bt_][r_] * Y_ + (C_ - 1.0f) * X_;                \
          float c2_  = num_ * fast_rcp(X_ * Y_);                               \
          cst[S][bt_][r_] = c2_;                                               \
          float cc_ = fminf(fmaxf(c2_, -40.0f), 40.0f);                        \
          float T_  = fast_exp2(2.88539008f * cc_);                            \
          float Eo_ = fast_exp2(-og_);                                         \
          float hv_ = (T_ - 1.0f) * fast_rcp((1.0f + Eo_) * (T_ + 1.0f));      \
          if (r_ == 0) h0_ = hv_; else if (r_ == 1) h1_ = hv_;                 \
          else if (r_ == 2) h2_ = hv_; else h3_ = hv_;                         \
        }                                                                      \
        lo_ = (u32)f16b(h0_) | ((u32)f16b(h1_) << 16);                         \
        hi_ = (u32)f16b(h2_) | ((u32)f16b(h3_) << 16);                         \
      }                                                                        \
      int c16_ = wv * 2 + (quad >> 1);                                         \
      int off_ = b_ * 128 + (c16_ ^ (b_ & 15)) * 8 + (quad & 1) * 4;           \
      *(uint2*)(lb_ + off_) = uint2{lo_, hi_};                                 \
      *(uint2*)(pb_ + off_) = uint2{lo_, hi_};                                 \
    }                                                                          \
  } while (0)

#pragma unroll 1
  for (int t = 0; t < 1024; ++t) {
    // ---- p1: g0 K(0,t) [lead] | g1 EW(1,t-1) + xcur[1] <- x_t ----
    if (grp == 0) {
      DO_K(0, t, 1);
    } else {
      if (t > 0) DO_EW(1, t - 1);
      xcur[1][0] = xq[(size_t)(32 + l15) * 1024 + t];
      xcur[1][1] = xq[(size_t)(48 + l15) * 1024 + t];
    }
    __syncthreads();
    if (tid == 0)  // h_t(1) complete (g0's EW@p4(t-1) + g1's EW@p1 drained)
      __hip_atomic_store(myflag + 16, t, __ATOMIC_RELAXED,
                         __HIP_MEMORY_SCOPE_AGENT);

    // ---- p2: g0 EW(0,t) | g1 K(0,t) ----
    if (grp == 0) DO_EW(0, t);
    else          DO_K(0, t, 0);
    __syncthreads();

    // ---- p3: g0 K(1,t) [lead] | g1 EW(0,t) + xcur[0] <- x_{t+1} ----
    if (grp == 0) {
      DO_K(1, t, 1);
    } else {
      DO_EW(0, t);
      xcur[0][0] = xq[(size_t)(l15) * 1024 + ((t + 1) & 1023)];
      xcur[0][1] = xq[(size_t)(16 + l15) * 1024 + ((t + 1) & 1023)];
    }
    __syncthreads();
    if (tid == 0)  // h_{t+1}(0) complete (g0's EW@p2 + g1's EW@p3 drained)
      __hip_atomic_store(myflag + 0, t + 1, __ATOMIC_RELAXED,
                         __HIP_MEMORY_SCOPE_AGENT);

    // ---- p4: g0 EW(1,t) + xcur both <- x_{t+1} | g1 K(1,t) ----
    if (grp == 0) {
      DO_EW(1, t);
      xcur[0][0] = xq[(size_t)(l15) * 1024 + ((t + 1) & 1023)];
      xcur[0][1] = xq[(size_t)(16 + l15) * 1024 + ((t + 1) & 1023)];
      xcur[1][0] = xq[(size_t)(32 + l15) * 1024 + ((t + 1) & 1023)];
      xcur[1][1] = xq[(size_t)(48 + l15) * 1024 + ((t + 1) & 1023)];
    } else {
      DO_K(1, t, 0);
    }
    __syncthreads();
  }

  // ---- epilogue: g1 still holds acc of K(1,1023) -> publish h_1024(1) ----
  if (grp == 1) DO_EW(1, 1023);
  __syncthreads();   // drains epilogue publish (implicit vmcnt(0))

  // ---- out[b] += (own j-half of h_1024) . Wout  (out pre-set to bout) ----
  if (tid < 64) {
    int s = tid >> 5, b = tid & 31;
    const u16* pbase = pub_base(pub, s, 0, pid, mi);  // parity of t=1024 is 0
    float a = 0.0f;
#pragma unroll
    for (int c = 0; c < 16; ++c) {
      f16x8 hv = *(const f16x8*)(pbase + b * 128 + ((c ^ (b & 15)) * 8));
#pragma unroll
      for (int e = 0; e < 8; ++e) a += (float)hv[e] * Wout[mi * 128 + c * 8 + e];
    }
    atomicAdd(&out[rows0 + s * 32 + b], a);
  }
#undef DO_K
#undef DO_EW
}

extern "C" void kernel_launch(void* const* d_in, const int* in_sizes, int n_in,
                              void* d_out, int out_size, void* d_ws, size_t ws_size,
                              hipStream_t stream) {
  const float* x    = (const float*)d_in[0];
  const float* Wf   = (const float*)d_in[1];
  const float* bf_  = (const float*)d_in[2];
  const float* Wi   = (const float*)d_in[3];
  const float* bi_  = (const float*)d_in[4];
  const float* Wc   = (const float*)d_in[5];
  const float* bc_  = (const float*)d_in[6];
  const float* Wo   = (const float*)d_in[7];
  const float* bo_  = (const float*)d_in[8];
  const float* Wout = (const float*)d_in[9];
  const float* bout = (const float*)d_in[10];

  u16* Wint  = (u16*)((char*)d_ws + WINT_OFF);
  u32* w0b   = (u32*)((char*)d_ws + W0B_OFF);
  int* flags = (int*)((char*)d_ws + FLAG_OFF);
  u16* pub   = (u16*)((char*)d_ws + PUB_OFF);

  lstm_prep<<<1024, 256, 0, stream>>>(Wf, Wi, Wc, Wo, bf_, bi_, bc_, bo_, Wint, w0b);
  lstm_zero<<<1064, 256, 0, stream>>>((uint4*)pub, (uint4*)flags, (float*)d_out, bout);
  lstm_main<<<256, 512, 0, stream>>>(Wint, w0b, x, Wout, (float*)d_out, pub, flags);
}